// Round 5
// baseline (3989.544 us; speedup 1.0000x reference)
//
#include <hip/hip_runtime.h>
#include <stdint.h>

typedef unsigned short u16;
typedef unsigned int   u32;
typedef __attribute__((ext_vector_type(8))) short short8;
typedef __attribute__((ext_vector_type(4))) float f32x4;

#define CAP   56

__device__ __forceinline__ u16 rne_bf16(float f){
  u32 u = __float_as_uint(f);
  u32 r = (u + 0x7fffu + ((u >> 16) & 1u)) >> 16;
  return (u16)r;
}
__device__ __forceinline__ float bf16_to_f(u16 h){
  return __uint_as_float(((u32)h) << 16);
}
__device__ __forceinline__ float tanh_fast(float x){
  float e = __expf(2.0f * x);
  return 1.0f - 2.0f / (e + 1.0f);
}

// ---------------------------------------------------------------------------
// A-pack: [xhi fbhi | xlo fblo], row m = b*1024+s, K=2048 bf16 bits
// ---------------------------------------------------------------------------
__global__ __launch_bounds__(256) void pack_a_k(const float* __restrict__ x,
                                                const float* __restrict__ fb,
                                                u16* __restrict__ A){
  int idx = blockIdx.x * 256 + threadIdx.x;          // 16384*512
  int m = idx >> 9, d = idx & 511;
  float xv = x[idx];
  float fv = fb[idx];
  u16 xh = rne_bf16(xv); u16 xl = rne_bf16(xv - bf16_to_f(xh));
  u16 fh = rne_bf16(fv); u16 fl = rne_bf16(fv - bf16_to_f(fh));
  size_t base = (size_t)m * 2048;
  A[base + d]        = xh;
  A[base + 512 + d]  = fh;
  A[base + 1024 + d] = xl;
  A[base + 1536 + d] = fl;
}

// ---------------------------------------------------------------------------
// B-pack with ROW PERMUTATION (col n of packed B = original row rowperm[n]).
// K=3072: [Winhi Wfbhi | Winhi Wfbhi | Winlo Wfblo]
// ---------------------------------------------------------------------------
__global__ __launch_bounds__(256) void pack_b_k(const float* __restrict__ Win,
                                                const float* __restrict__ Wfb,
                                                const int* __restrict__ rowperm,
                                                u16* __restrict__ Bm){
  int idx = blockIdx.x * 256 + threadIdx.x;          // 2048*512
  int n = idx >> 9, d = idx & 511;
  int row = rowperm[n];
  float iv = Win[(size_t)row * 512 + d];
  float fv = Wfb[(size_t)row * 512 + d];
  u16 ih = rne_bf16(iv); u16 il = rne_bf16(iv - bf16_to_f(ih));
  u16 fh = rne_bf16(fv); u16 fl = rne_bf16(fv - bf16_to_f(fh));
  size_t base = (size_t)n * 3072;
  Bm[base + d]        = ih;
  Bm[base + 512 + d]  = fh;
  Bm[base + 1024 + d] = ih;
  Bm[base + 1536 + d] = fh;
  Bm[base + 2048 + d] = il;
  Bm[base + 2560 + d] = fl;
}

// ---------------------------------------------------------------------------
// Drive GEMM: M=16384,N=2048,K=3072, 128x128 tile, plain coalesced stores.
// ---------------------------------------------------------------------------
#define GLDS(gp, lp) __builtin_amdgcn_global_load_lds( \
    (const __attribute__((address_space(1))) void*)(gp), \
    (__attribute__((address_space(3))) void*)(lp), 16, 0, 0)

__global__ __launch_bounds__(256) void gemm_k(const u16* __restrict__ A,
                                              const u16* __restrict__ Bm,
                                              float* __restrict__ C){
  __shared__ __align__(16) u16 As[128 * 32];
  __shared__ __align__(16) u16 Bs[128 * 32];
  const int tid = threadIdx.x;
  const int w = tid >> 6, l = tid & 63;
  const int bid = blockIdx.x;
  const int mt = bid >> 4, nt = bid & 15;
  const int m0 = mt * 128, n0 = nt * 128;
  const int srow = tid >> 2;
  const int scol = (tid & 3) * 8;
  const int wr = w & 1, wc = w >> 1;
  const int lhi = l >> 4, llo = l & 15;

  f32x4 acc[4][4];
  #pragma unroll
  for (int i = 0; i < 4; i++)
    #pragma unroll
    for (int j = 0; j < 4; j++)
      acc[i][j] = (f32x4){0.f, 0.f, 0.f, 0.f};

  for (int kt = 0; kt < 96; ++kt){
    int k = kt * 32;
    int keff = (k >= 2048) ? (k - 2048) : k;
    #pragma unroll
    for (int r = 0; r < 2; r++){
      const u16* ga = A  + (size_t)(m0 + r * 64 + srow) * 2048 + keff + scol;
      GLDS(ga, &As[r * 2048 + w * 512]);
      const u16* gb = Bm + (size_t)(n0 + r * 64 + srow) * 3072 + k + scol;
      GLDS(gb, &Bs[r * 2048 + w * 512]);
    }
    __syncthreads();
    short8 af[4], bf[4];
    #pragma unroll
    for (int i = 0; i < 4; i++){
      af[i] = *(const short8*)&As[(wr * 64 + i * 16 + llo) * 32 + lhi * 8];
      bf[i] = *(const short8*)&Bs[(wc * 64 + i * 16 + llo) * 32 + lhi * 8];
    }
    #pragma unroll
    for (int i = 0; i < 4; i++)
      #pragma unroll
      for (int j = 0; j < 4; j++)
        acc[i][j] = __builtin_amdgcn_mfma_f32_16x16x32_bf16(af[i], bf[j], acc[i][j], 0, 0, 0);
    __syncthreads();
  }
  #pragma unroll
  for (int i = 0; i < 4; i++)
    #pragma unroll
    for (int j = 0; j < 4; j++)
      #pragma unroll
      for (int rg = 0; rg < 4; rg++){
        int mr = m0 + wr * 64 + i * 16 + lhi * 4 + rg;
        int nc = n0 + wc * 64 + j * 16 + llo;
        C[(size_t)mr * 2048 + nc] = acc[i][j][rg];
      }
}

// ---------------------------------------------------------------------------
// count nnz per row (one wave per row)
// ---------------------------------------------------------------------------
__global__ __launch_bounds__(256) void count_k(const float* __restrict__ W,
                                               int* __restrict__ nnz){
  int gt = blockIdx.x * 256 + threadIdx.x;
  int row = gt >> 6, l = gt & 63;
  const float* wr = W + (size_t)row * 2048;
  int c = 0;
  for (int i = 0; i < 32; i++) c += (wr[i * 64 + l] != 0.0f) ? 1 : 0;
  for (int off = 32; off; off >>= 1) c += __shfl_down(c, off, 64);
  if (l == 0) nnz[row] = c;
}

// ---------------------------------------------------------------------------
// PER-HALF counting sort (rows [0,1024) and [1024,2048) separately), desc by
// nnz, pair i <-> 1023-i within the half. Pair q = h*512+i belongs to rnn
// block h. Drive columns for pair q: colA = h*1024+i, colB = h*1024+512+i
// (both inside block h's own column range -> zero cross-block line sharing).
// Also zeroes the rnn sync flags each launch.
// ---------------------------------------------------------------------------
__global__ __launch_bounds__(1024) void sort_k(const int* __restrict__ nnz,
                                               u32* __restrict__ rowsp,
                                               int* __restrict__ L1a,
                                               int* __restrict__ rowperm,
                                               int* __restrict__ flags){
  __shared__ int hist[128], off[128], cur[128];
  __shared__ int order[2048];
  int tid = threadIdx.x;
  if (tid < 32) flags[tid] = 0;
  if (tid < 128){ hist[tid] = 0; cur[tid] = 0; }
  __syncthreads();
  {
    int b0 = nnz[tid]; if (b0 > 63) b0 = 63;
    atomicAdd(&hist[b0], 1);
    int b1 = nnz[tid + 1024]; if (b1 > 63) b1 = 63;
    atomicAdd(&hist[64 + b1], 1);
  }
  __syncthreads();
  if (tid < 2){
    int run = 0;
    for (int b = 63; b >= 0; b--){ off[tid * 64 + b] = run; run += hist[tid * 64 + b]; }
  }
  __syncthreads();
  {
    int b0 = nnz[tid]; if (b0 > 63) b0 = 63;
    int pos = off[b0] + atomicAdd(&cur[b0], 1);
    order[pos] = tid;
    int b1 = nnz[tid + 1024]; if (b1 > 63) b1 = 63;
    int pos1 = off[64 + b1] + atomicAdd(&cur[64 + b1], 1);
    order[1024 + pos1] = tid + 1024;
  }
  __syncthreads();
  int hh = tid >> 9, ii = tid & 511;                 // q == tid
  int rA = order[hh * 1024 + ii];
  int rB = order[hh * 1024 + 1023 - ii];
  rowsp[tid] = (u32)rA | ((u32)rB << 16);
  L1a[tid] = nnz[rA];
  rowperm[hh * 1024 + ii] = rA;
  rowperm[hh * 1024 + 512 + ii] = rB;
}

// ---------------------------------------------------------------------------
// Fill RAW per-thread item words (slot-major over 1024 pairs):
// [0,L1)=rowA items, [L1,..)=rowB. raw = rounded value bits | column (11 b).
// ---------------------------------------------------------------------------
__global__ __launch_bounds__(256) void fill_k(const float* __restrict__ W,
                                              const u32* __restrict__ rowsp,
                                              u32* __restrict__ raw){
  int gt = blockIdx.x * 256 + threadIdx.x;
  int p = gt >> 6, l = gt & 63;
  u32 rp = rowsp[p];
  int rA = (int)(rp & 0xffffu), rB = (int)(rp >> 16);
  int base = 0;
  for (int h = 0; h < 2; h++){
    int row = h ? rB : rA;
    const float* wr = W + (size_t)row * 2048;
    int cnt = 0;
    for (int i = 0; i < 32; i++){
      int c = i * 64 + l;
      float v = wr[c];
      unsigned long long m = __ballot(v != 0.0f);
      int pre = __popcll(m & ((1ull << l) - 1ull));
      if (v != 0.0f){
        int s = base + cnt + pre;
        if (s < CAP){
          u32 u = __float_as_uint(v);
          u = ((u + 0x1000u) & 0xFFFFE000u) | (u32)c;
          raw[s * 1024 + p] = u;
        }
      }
      cnt += __popcll(m);
    }
    base += cnt;
  }
}

// ---------------------------------------------------------------------------
// Greedy bank scheduler (round-2 proven). One wave per rnn wave-group of 64
// pairs. Capacity-2 first-fit per (slot,bank), relax when stuck; pads target
// underfull banks. Emits compensated (value,addr) words.
// ---------------------------------------------------------------------------
__global__ __launch_bounds__(64) void sched_k(const u32* __restrict__ raw,
                                              u32* __restrict__ wpk,
                                              const u32* __restrict__ rowsp,
                                              const int* __restrict__ nnz){
  __shared__ u32 pool[CAP * 64];
  __shared__ int cnt[32];
  const int lane = threadIdx.x;
  const int p = blockIdx.x * 64 + lane;
  u32 rp = rowsp[p];
  int rA = (int)(rp & 0xffffu), rB = (int)(rp >> 16);
  int L1 = nnz[rA]; if (L1 > CAP) L1 = CAP;
  int nT = L1 + nnz[rB]; if (nT > CAP) nT = CAP;
  for (int k = 0; k < CAP; k++) pool[k * 64 + lane] = raw[k * 1024 + p];
  __syncthreads();
  unsigned long long used = 0ull;
  for (int s = 0; s < CAP; s++){
    if (lane < 32) cnt[lane] = 0;
    __syncthreads();
    u32 word;
    if (s < nT){
      int lo = (s < L1) ? 0 : L1;
      int hi = (s < L1) ? L1 : nT;
      int chosen = -1;
      for (int capc = 2; chosen < 0; capc++){
        for (int j = lo; j < hi; j++){
          if (used & (1ull << j)) continue;
          int bk = (int)(pool[j * 64 + lane] & 31u);
          int old = atomicAdd(&cnt[bk], 1);
          if (old < capc){ chosen = j; break; }
          atomicSub(&cnt[bk], 1);
        }
      }
      used |= 1ull << chosen;
      u32 r = pool[chosen * 64 + lane];
      u32 vb = r & 0xFFFFE000u;
      u32 ad = (r & 0x7FFu) << 2;
      word = ((vb - ad + 0x1000u) & 0xFFFFE000u) + ad;
    } else {
      int bsel = -1;
      for (int capc = 2; bsel < 0; capc++){
        for (int bb = 0; bb < 32; bb++){
          int bk = (bb + lane) & 31;
          int old = atomicAdd(&cnt[bk], 1);
          if (old < capc){ bsel = bk; break; }
          atomicSub(&cnt[bk], 1);
        }
      }
      word = (u32)bsel << 2;                         // denormal value ~ 0
    }
    __syncthreads();
    wpk[s * 1024 + p] = word;
  }
}

// ---------------------------------------------------------------------------
// Recurrent kernel, 2 CUs PER BATCH: 32 blocks x 512 threads. Block (b,h)
// owns rows [h*1024,(h+1)*1024). Per step: gather from full LDS state,
// write own states to out[t] (dense scattered NT) + own LDS half, vmcnt(0),
// post flag, lane0 spins on peer flag (same-XCD L2), re-import peer 4KB
// from out[t] (coalesced, never-in-L1 addresses). Drive columns are block-
// local by rowperm construction -> no cross-block write/read collisions.
// ---------------------------------------------------------------------------
__global__ __attribute__((amdgpu_flat_work_group_size(512, 512),
                          amdgpu_waves_per_eu(2, 2)))
void rnn_k(float* __restrict__ out,
           const float* __restrict__ init,
           const u32* __restrict__ wpkg,
           const u32* __restrict__ rowsp,
           const int* __restrict__ L1a,
           int* flags){
  const int tid = threadIdx.x;
  const int b = blockIdx.x & 15, h = blockIdx.x >> 4;
  const int q = h * 512 + tid;                       // pair index
  u32 wk[CAP];
  #pragma unroll
  for (int k = 0; k < CAP; k++) wk[k] = wpkg[k * 1024 + q];
  u32 rp = rowsp[q];
  const int rA = (int)(rp & 0xffffu), rB = (int)(rp >> 16);
  const int L1 = L1a[q];
  const int own0 = h << 10, peer0 = (1 - h) << 10;

  __shared__ float st[2048];
  #pragma unroll
  for (int j = 0; j < 4; j++)
    st[j * 512 + tid] = init[(size_t)b * 2048 + j * 512 + tid];
  __syncthreads();
  const char* stb = (const char*)st;

  float* ob = out + (size_t)b * 1024 * 2048;
  int* myf = &flags[h * 16 + b];
  int* pf  = &flags[(1 - h) * 16 + b];

  float dA = __builtin_nontemporal_load(&ob[own0 + tid]);
  float dB = __builtin_nontemporal_load(&ob[own0 + 512 + tid]);

  for (int t = 0; t < 1024; t++){
    float* row = ob + (size_t)t * 2048;
    const float* nrow = ob + (size_t)((t + 1) & 1023) * 2048;
    float dA2 = __builtin_nontemporal_load(&nrow[own0 + tid]);   // own cols
    float dB2 = __builtin_nontemporal_load(&nrow[own0 + 512 + tid]);
    float aAll = 0.f, aA = 0.f;
    #pragma unroll
    for (int k = 0; k < CAP; k++){
      u32 w = wk[k];
      float sv = *(const float*)(stb + (w & 0x1FFCu));
      float pv = __uint_as_float(w) * sv;
      aAll += pv;
      aA += (k < L1) ? pv : 0.0f;
    }
    float sA = tanh_fast(aA + dA);
    float sB = tanh_fast((aAll - aA) + dB);
    __builtin_nontemporal_store(sA, &row[rA]);       // own rows, dense 4KB
    __builtin_nontemporal_store(sB, &row[rB]);
    __syncthreads();                                 // all gathers done
    st[rA] = sA; st[rB] = sB;                        // own LDS half
    asm volatile("s_waitcnt vmcnt(0)" ::: "memory"); // stores+prefetch drained
    if (tid == 0){
      __hip_atomic_store(myf, t + 1, __ATOMIC_RELAXED, __HIP_MEMORY_SCOPE_AGENT);
      while (__hip_atomic_load(pf, __ATOMIC_ACQUIRE, __HIP_MEMORY_SCOPE_AGENT) <= t)
        __builtin_amdgcn_s_sleep(1);
    }
    __syncthreads();                                 // peer states in L2
    float p0 = __builtin_nontemporal_load(&row[peer0 + tid]);
    float p1 = __builtin_nontemporal_load(&row[peer0 + 512 + tid]);
    st[peer0 + tid] = p0;
    st[peer0 + 512 + tid] = p1;
    __syncthreads();                                 // full state for t+1
    dA = dA2; dB = dB2;
  }
}

// ---------------------------------------------------------------------------
extern "C" void kernel_launch(void* const* d_in, const int* in_sizes, int n_in,
                              void* d_out, int out_size, void* d_ws, size_t ws_size,
                              hipStream_t stream) {
  const float* x    = (const float*)d_in[0];
  const float* fb   = (const float*)d_in[1];
  const float* init = (const float*)d_in[2];
  const float* Wres = (const float*)d_in[3];
  const float* Win  = (const float*)d_in[4];
  const float* Wfb  = (const float*)d_in[5];
  float* out = (float*)d_out;

  char* w8 = (char*)d_ws;
  u16*  A_pack = (u16*)(w8);                       // 67108864 B
  u16*  B_pack = (u16*)(w8 + 67108864);            // 12582912 B
  u32*  wpk    = (u32*) (w8 + 79691776);           // 56*1024*4 = 229376
  int*  nnz    = (int*) (w8 + 79921152);           // 8192
  u32*  rowsp  = (u32*) (w8 + 79929344);           // 4096
  int*  L1a    = (int*) (w8 + 79933440);           // 4096
  int*  rowperm= (int*) (w8 + 79937536);           // 8192
  int*  flags  = (int*) (w8 + 79945728);           // 128
  u32*  raw    = (u32*) out;                       // dead before gemm writes

  pack_a_k<<<32768, 256, 0, stream>>>(x, fb, A_pack);
  count_k<<<512, 256, 0, stream>>>(Wres, nnz);
  sort_k<<<1, 1024, 0, stream>>>(nnz, rowsp, L1a, rowperm, flags);
  pack_b_k<<<4096, 256, 0, stream>>>(Win, Wfb, rowperm, B_pack);
  fill_k<<<256, 256, 0, stream>>>(Wres, rowsp, raw);
  sched_k<<<16, 64, 0, stream>>>(raw, wpk, rowsp, nnz);
  gemm_k<<<2048, 256, 0, stream>>>(A_pack, B_pack, out);
  rnn_k<<<32, 512, 0, stream>>>(out, init, wpk, rowsp, L1a, flags);
}

// Round 6
// 3085.451 us; speedup vs baseline: 1.2930x; 1.2930x over previous
//
#include <hip/hip_runtime.h>
#include <stdint.h>

typedef unsigned short u16;
typedef unsigned int   u32;
typedef __attribute__((ext_vector_type(8))) short short8;
typedef __attribute__((ext_vector_type(4))) float f32x4;

#define CAP   52

__device__ __forceinline__ u16 rne_bf16(float f){
  u32 u = __float_as_uint(f);
  u32 r = (u + 0x7fffu + ((u >> 16) & 1u)) >> 16;
  return (u16)r;
}
__device__ __forceinline__ float bf16_to_f(u16 h){
  return __uint_as_float(((u32)h) << 16);
}
__device__ __forceinline__ float tanh_fast(float x){
  float e = __expf(2.0f * x);
  return 1.0f - 2.0f / (e + 1.0f);
}

// ---------------------------------------------------------------------------
// A-pack: [xhi fbhi | xlo fblo], row m = b*1024+s, K=2048 bf16 bits
// ---------------------------------------------------------------------------
__global__ __launch_bounds__(256) void pack_a_k(const float* __restrict__ x,
                                                const float* __restrict__ fb,
                                                u16* __restrict__ A){
  int idx = blockIdx.x * 256 + threadIdx.x;          // 16384*512
  int m = idx >> 9, d = idx & 511;
  float xv = x[idx];
  float fv = fb[idx];
  u16 xh = rne_bf16(xv); u16 xl = rne_bf16(xv - bf16_to_f(xh));
  u16 fh = rne_bf16(fv); u16 fl = rne_bf16(fv - bf16_to_f(fh));
  size_t base = (size_t)m * 2048;
  A[base + d]        = xh;
  A[base + 512 + d]  = fh;
  A[base + 1024 + d] = xl;
  A[base + 1536 + d] = fl;
}

// ---------------------------------------------------------------------------
// B-pack with ROW PERMUTATION (col n of packed B = original row rowperm[n]).
// K=3072: [Winhi Wfbhi | Winhi Wfbhi | Winlo Wfblo]
// ---------------------------------------------------------------------------
__global__ __launch_bounds__(256) void pack_b_k(const float* __restrict__ Win,
                                                const float* __restrict__ Wfb,
                                                const int* __restrict__ rowperm,
                                                u16* __restrict__ Bm){
  int idx = blockIdx.x * 256 + threadIdx.x;          // 2048*512
  int n = idx >> 9, d = idx & 511;
  int row = rowperm[n];
  float iv = Win[(size_t)row * 512 + d];
  float fv = Wfb[(size_t)row * 512 + d];
  u16 ih = rne_bf16(iv); u16 il = rne_bf16(iv - bf16_to_f(ih));
  u16 fh = rne_bf16(fv); u16 fl = rne_bf16(fv - bf16_to_f(fh));
  size_t base = (size_t)n * 3072;
  Bm[base + d]        = ih;
  Bm[base + 512 + d]  = fh;
  Bm[base + 1024 + d] = ih;
  Bm[base + 1536 + d] = fh;
  Bm[base + 2048 + d] = il;
  Bm[base + 2560 + d] = fl;
}

// ---------------------------------------------------------------------------
// Drive GEMM: M=16384,N=2048,K=3072, 128x128 tile, plain coalesced stores.
// ---------------------------------------------------------------------------
#define GLDS(gp, lp) __builtin_amdgcn_global_load_lds( \
    (const __attribute__((address_space(1))) void*)(gp), \
    (__attribute__((address_space(3))) void*)(lp), 16, 0, 0)

__global__ __launch_bounds__(256) void gemm_k(const u16* __restrict__ A,
                                              const u16* __restrict__ Bm,
                                              float* __restrict__ C){
  __shared__ __align__(16) u16 As[128 * 32];
  __shared__ __align__(16) u16 Bs[128 * 32];
  const int tid = threadIdx.x;
  const int w = tid >> 6, l = tid & 63;
  const int bid = blockIdx.x;
  const int mt = bid >> 4, nt = bid & 15;
  const int m0 = mt * 128, n0 = nt * 128;
  const int srow = tid >> 2;
  const int scol = (tid & 3) * 8;
  const int wr = w & 1, wc = w >> 1;
  const int lhi = l >> 4, llo = l & 15;

  f32x4 acc[4][4];
  #pragma unroll
  for (int i = 0; i < 4; i++)
    #pragma unroll
    for (int j = 0; j < 4; j++)
      acc[i][j] = (f32x4){0.f, 0.f, 0.f, 0.f};

  for (int kt = 0; kt < 96; ++kt){
    int k = kt * 32;
    int keff = (k >= 2048) ? (k - 2048) : k;
    #pragma unroll
    for (int r = 0; r < 2; r++){
      const u16* ga = A  + (size_t)(m0 + r * 64 + srow) * 2048 + keff + scol;
      GLDS(ga, &As[r * 2048 + w * 512]);
      const u16* gb = Bm + (size_t)(n0 + r * 64 + srow) * 3072 + k + scol;
      GLDS(gb, &Bs[r * 2048 + w * 512]);
    }
    __syncthreads();
    short8 af[4], bf[4];
    #pragma unroll
    for (int i = 0; i < 4; i++){
      af[i] = *(const short8*)&As[(wr * 64 + i * 16 + llo) * 32 + lhi * 8];
      bf[i] = *(const short8*)&Bs[(wc * 64 + i * 16 + llo) * 32 + lhi * 8];
    }
    #pragma unroll
    for (int i = 0; i < 4; i++)
      #pragma unroll
      for (int j = 0; j < 4; j++)
        acc[i][j] = __builtin_amdgcn_mfma_f32_16x16x32_bf16(af[i], bf[j], acc[i][j], 0, 0, 0);
    __syncthreads();
  }
  #pragma unroll
  for (int i = 0; i < 4; i++)
    #pragma unroll
    for (int j = 0; j < 4; j++)
      #pragma unroll
      for (int rg = 0; rg < 4; rg++){
        int mr = m0 + wr * 64 + i * 16 + lhi * 4 + rg;
        int nc = n0 + wc * 64 + j * 16 + llo;
        C[(size_t)mr * 2048 + nc] = acc[i][j][rg];
      }
}

// ---------------------------------------------------------------------------
// count nnz per row (one wave per row)
// ---------------------------------------------------------------------------
__global__ __launch_bounds__(256) void count_k(const float* __restrict__ W,
                                               int* __restrict__ nnz){
  int gt = blockIdx.x * 256 + threadIdx.x;
  int row = gt >> 6, l = gt & 63;
  const float* wr = W + (size_t)row * 2048;
  int c = 0;
  for (int i = 0; i < 32; i++) c += (wr[i * 64 + l] != 0.0f) ? 1 : 0;
  for (int off = 32; off; off >>= 1) c += __shfl_down(c, off, 64);
  if (l == 0) nnz[row] = c;
}

// ---------------------------------------------------------------------------
// Counting-sort rows desc by nnz, pair p <-> 2047-p; emit rowperm for pack_b.
// ---------------------------------------------------------------------------
__global__ __launch_bounds__(1024) void sort_k(const int* __restrict__ nnz,
                                               u32* __restrict__ rowsp,
                                               int* __restrict__ L1a,
                                               int* __restrict__ rowperm){
  __shared__ int hist[64], off[64], cur[64];
  __shared__ int order[2048];
  int tid = threadIdx.x;
  if (tid < 64){ hist[tid] = 0; cur[tid] = 0; }
  __syncthreads();
  for (int r = tid; r < 2048; r += 1024){
    int b = nnz[r]; if (b > 63) b = 63;
    atomicAdd(&hist[b], 1);
  }
  __syncthreads();
  if (tid == 0){
    int run = 0;
    for (int b = 63; b >= 0; b--){ off[b] = run; run += hist[b]; }
  }
  __syncthreads();
  for (int r = tid; r < 2048; r += 1024){
    int b = nnz[r]; if (b > 63) b = 63;
    int pos = off[b] + atomicAdd(&cur[b], 1);
    order[pos] = r;
  }
  __syncthreads();
  int rA = order[tid], rB = order[2047 - tid];
  rowsp[tid] = (u32)rA | ((u32)rB << 16);
  L1a[tid] = nnz[rA];
  rowperm[tid] = rA;
  rowperm[tid + 1024] = rB;
}

// ---------------------------------------------------------------------------
// Fill RAW per-thread item words (slot-major): [0,L1)=rowA, [L1,..)=rowB.
// raw = (value bits rounded at 10-bit mantissa, bits 31:13) | column (11 b).
// sched_k assigns slots + does the final compensation.
// ---------------------------------------------------------------------------
__global__ __launch_bounds__(256) void fill_k(const float* __restrict__ W,
                                              const u32* __restrict__ rowsp,
                                              u32* __restrict__ raw){
  int gt = blockIdx.x * 256 + threadIdx.x;
  int p = gt >> 6, l = gt & 63;
  u32 rp = rowsp[p];
  int rA = (int)(rp & 0xffffu), rB = (int)(rp >> 16);
  int base = 0;
  for (int h = 0; h < 2; h++){
    int row = h ? rB : rA;
    const float* wr = W + (size_t)row * 2048;
    int cnt = 0;
    for (int i = 0; i < 32; i++){
      int c = i * 64 + l;
      float v = wr[c];
      unsigned long long m = __ballot(v != 0.0f);
      int pre = __popcll(m & ((1ull << l) - 1ull));
      if (v != 0.0f){
        int s = base + cnt + pre;
        if (s < CAP){
          u32 u = __float_as_uint(v);
          u = ((u + 0x1000u) & 0xFFFFE000u) | (u32)c;
          raw[s * 1024 + p] = u;
        }
      }
      cnt += __popcll(m);
    }
    base += cnt;
  }
}

// ---------------------------------------------------------------------------
// HALF-WAVE-PHASE BANK SCHEDULER. One 64-lane wave per rnn wave (16 blocks,
// barrier-free: wave64 lockstep, LDS ops complete in order per wave).
// HW model: a wave64 ds_read_b32 executes as TWO 32-lane phases (lanes 0-31,
// then 32-63); 256B/clk LDS = 32 b32 lanes/cycle. Bank conflicts are
// WITHIN-PHASE, so "cap 2 per wave" (rounds 2-4) allowed same-half pairs =
// real 2-way conflicts ~half the time. Correct constraint: <=1 user per
// (half-wave, bank) per slot. cnt[64] = (lane>>5)*32 + bank, capacity 1,
// relax only when a lane's remaining items can't fit. Pads fill their own
// half's empty banks. Item order permuted only within segments
// ([0,L1)=rowA) -> rnn semantics untouched.
// Output: compensated word (low 13 bits byte addr, float(word) ~ weight).
// ---------------------------------------------------------------------------
__global__ __launch_bounds__(64) void sched_k(const u32* __restrict__ raw,
                                              u32* __restrict__ wpk,
                                              const u32* __restrict__ rowsp,
                                              const int* __restrict__ nnz){
  __shared__ u32 pool[CAP * 64];
  __shared__ int cnt[64];                            // [half*32 + bank]
  const int lane = threadIdx.x;
  const int p = blockIdx.x * 64 + lane;
  const int hb = (lane >> 5) << 5;                   // my half's base (0|32)
  u32 rp = rowsp[p];
  int rA = (int)(rp & 0xffffu), rB = (int)(rp >> 16);
  int L1 = nnz[rA]; if (L1 > CAP) L1 = CAP;
  int nT = L1 + nnz[rB]; if (nT > CAP) nT = CAP;
  for (int k = 0; k < CAP; k++) pool[k * 64 + lane] = raw[k * 1024 + p];

  unsigned long long used = 0ull;
  for (int s = 0; s < CAP; s++){
    cnt[lane] = 0;                                   // 64 lanes reset 64 cells
    u32 word;
    if (s < nT){
      int lo = (s < L1) ? 0 : L1;
      int hi = (s < L1) ? L1 : nT;
      int chosen = -1;
      for (int capc = 1; chosen < 0; capc++){
        for (int j = lo; j < hi; j++){
          if (used & (1ull << j)) continue;
          int bk = (int)(pool[j * 64 + lane] & 31u);
          int old = atomicAdd(&cnt[hb + bk], 1);
          if (old < capc){ chosen = j; break; }
          atomicSub(&cnt[hb + bk], 1);
        }
      }
      used |= 1ull << chosen;
      u32 r = pool[chosen * 64 + lane];
      u32 vb = r & 0xFFFFE000u;
      u32 ad = (r & 0x7FFu) << 2;
      word = ((vb - ad + 0x1000u) & 0xFFFFE000u) + ad;
    } else {
      int bsel = -1;
      for (int capc = 1; bsel < 0; capc++){
        for (int bb = 0; bb < 32; bb++){
          int bk = (bb + lane) & 31;
          int old = atomicAdd(&cnt[hb + bk], 1);
          if (old < capc){ bsel = bk; break; }
          atomicSub(&cnt[hb + bk], 1);
        }
      }
      word = (u32)bsel << 2;                         // denormal value ~ 0
    }
    wpk[s * 1024 + p] = word;
  }
}

// ---------------------------------------------------------------------------
// Recurrent kernel (byte-identical to round 2's proven 2343 us version):
// 16 WGs, 1024 thr, state in LDS, 52 packed u32 in registers, compensated
// value encoding, drive prefetch, 2 barriers/step.
// ---------------------------------------------------------------------------
__global__ __attribute__((amdgpu_flat_work_group_size(1024, 1024),
                          amdgpu_waves_per_eu(4, 4)))
void rnn_k(float* __restrict__ out,
           const float* __restrict__ init,
           const u32* __restrict__ wpkg,
           const u32* __restrict__ rowsp,
           const int* __restrict__ L1a){
  const int tid = threadIdx.x, b = blockIdx.x;
  u32 wk[CAP];
  #pragma unroll
  for (int k = 0; k < CAP; k++) wk[k] = wpkg[k * 1024 + tid];
  u32 rp = rowsp[tid];
  int rA = (int)(rp & 0xffffu), rB = (int)(rp >> 16);
  int L1 = L1a[tid];

  __shared__ float st[2048];
  st[tid]        = init[(size_t)b * 2048 + tid];
  st[tid + 1024] = init[(size_t)b * 2048 + tid + 1024];
  __syncthreads();
  const char* stb = (const char*)st;

  float* ob = out + (size_t)b * 1024 * 2048;
  float dA = __builtin_nontemporal_load(&ob[tid]);
  float dB = __builtin_nontemporal_load(&ob[tid + 1024]);
  for (int t = 0; t < 1024; t++){
    float* orow = ob + (size_t)t * 2048;
    const float* nrow = ob + (size_t)((t + 1) & 1023) * 2048;
    float dA2 = __builtin_nontemporal_load(&nrow[tid]);        // prefetch t+1
    float dB2 = __builtin_nontemporal_load(&nrow[tid + 1024]);
    float aAll = 0.f, aA = 0.f;
    #pragma unroll
    for (int k = 0; k < CAP; k++){
      u32 w = wk[k];
      float sv = *(const float*)(stb + (w & 0x1FFCu));
      float pv = __uint_as_float(w) * sv;
      aAll += pv;
      aA += (k < L1) ? pv : 0.0f;
    }
    float preA = aA + dA;                 // consume drive BEFORE barrier
    float preB = (aAll - aA) + dB;
    __syncthreads();                      // all st reads done
    float sA = tanh_fast(preA);
    float sB = tanh_fast(preB);
    st[rA] = sA; st[rB] = sB;
    __syncthreads();                      // new state visible
    __builtin_nontemporal_store(st[tid], &orow[tid]);          // coalesced
    __builtin_nontemporal_store(st[tid + 1024], &orow[tid + 1024]);
    dA = dA2; dB = dB2;
  }
}

// ---------------------------------------------------------------------------
extern "C" void kernel_launch(void* const* d_in, const int* in_sizes, int n_in,
                              void* d_out, int out_size, void* d_ws, size_t ws_size,
                              hipStream_t stream) {
  const float* x    = (const float*)d_in[0];
  const float* fb   = (const float*)d_in[1];
  const float* init = (const float*)d_in[2];
  const float* Wres = (const float*)d_in[3];
  const float* Win  = (const float*)d_in[4];
  const float* Wfb  = (const float*)d_in[5];
  float* out = (float*)d_out;

  char* w8 = (char*)d_ws;
  u16*  A_pack = (u16*)(w8);                       // 67108864 B
  u16*  B_pack = (u16*)(w8 + 67108864);            // 12582912 B
  u32*  wpk    = (u32*) (w8 + 79691776);           // 52*1024*4 = 212992
  int*  nnz    = (int*) (w8 + 79904768);           // 8192
  u32*  rowsp  = (u32*) (w8 + 79912960);           // 4096
  int*  L1a    = (int*) (w8 + 79917056);           // 4096
  int*  rowperm= (int*) (w8 + 79921152);           // 8192
  u32*  raw    = (u32*) out;                       // dead before gemm writes

  pack_a_k<<<32768, 256, 0, stream>>>(x, fb, A_pack);
  count_k<<<512, 256, 0, stream>>>(Wres, nnz);
  sort_k<<<1, 1024, 0, stream>>>(nnz, rowsp, L1a, rowperm);
  pack_b_k<<<4096, 256, 0, stream>>>(Win, Wfb, rowperm, B_pack);
  fill_k<<<256, 256, 0, stream>>>(Wres, rowsp, raw);
  sched_k<<<16, 64, 0, stream>>>(raw, wpk, rowsp, nnz);
  gemm_k<<<2048, 256, 0, stream>>>(A_pack, B_pack, out);
  rnn_k<<<16, 1024, 0, stream>>>(out, init, wpk, rowsp, L1a);
}